// Round 4
// baseline (35.857 us; speedup 1.0000x reference)
//
#include <hip/hip_runtime.h>
#include <math.h>

#define TPB 512
#define WAVES 8
#define RAYS_PB 256      // rays per block
#define RPT 4            // rays per thread (RAYS_PB / 64)
#define PREP_BLK 16      // prep blocks per batch
#define PREP_T 128

// ---------------------------------------------------------------------------
// Prep: pack points as (qx,qy,qz,-0.5|q|^2); per-block maxdist^2 partials.
// grid = (PREP_BLK, B), block = 128. No atomics, no memset.
// ---------------------------------------------------------------------------
__global__ __launch_bounds__(PREP_T) void prep_kernel(
    const float* __restrict__ c, const float* __restrict__ pc,
    float4* __restrict__ pts4, float* __restrict__ gpart, int N)
{
    int b = blockIdx.y, blk = blockIdx.x;
    const float* cb = c + b * 25;
    float ox = cb[3], oy = cb[7], oz = cb[11];
    const float* p = pc + (size_t)b * N * 3;
    int per = (N + PREP_BLK - 1) / PREP_BLK;
    int n0 = blk * per;
    int n1 = min(n0 + per, N);
    float mx = 0.0f;   // squared distances are >= 0
    for (int n = n0 + threadIdx.x; n < n1; n += PREP_T) {
        float qx = p[n * 3], qy = p[n * 3 + 1], qz = p[n * 3 + 2];
        float qn = qx * qx + qy * qy + qz * qz;
        pts4[(size_t)b * N + n] = make_float4(qx, qy, qz, -0.5f * qn);
        float dx = qx - ox, dy = qy - oy, dz = qz - oz;
        mx = fmaxf(mx, dx * dx + dy * dy + dz * dz);
    }
    for (int off = 32; off; off >>= 1) mx = fmaxf(mx, __shfl_down(mx, off));
    __shared__ float sm[PREP_T / 64];
    if ((threadIdx.x & 63) == 0) sm[threadIdx.x >> 6] = mx;
    __syncthreads();
    if (threadIdx.x == 0) {
        float m2 = sm[0];
        for (int i = 1; i < PREP_T / 64; ++i) m2 = fmaxf(m2, sm[i]);
        gpart[b * PREP_BLK + blk] = m2;
    }
}

// ---------------------------------------------------------------------------
// Main: grid = (ceil(M/256), B), block = 512 (8 waves).
// Block covers 256 rays vs ALL N points. Wave w scans points [w*N/8, ...)
// via wave-uniform broadcast global loads (no LDS staging, no in-loop
// barriers). 4 rays/thread in registers. Cross-wave max combine in LDS,
// then in-block masked sum -> one float2 partial per block. Deterministic.
//   min_n d2 = pn - 2 * max_n (p.q - 0.5|q|^2),  q.w = -0.5|q|^2
// ---------------------------------------------------------------------------
__global__ __launch_bounds__(TPB) void chamfer_main(
    const float* __restrict__ c, const float* __restrict__ depth,
    const float4* __restrict__ pts4, const float* __restrict__ gpart,
    float2* __restrict__ partial, int res, int M, int N)
{
    __shared__ float red[WAVES][RAYS_PB];    // 8 KB
    __shared__ float bs[RPT], bc[RPT];

    int tile = blockIdx.x, b = blockIdx.y;
    int tid = threadIdx.x, w = tid >> 6, lane = tid & 63;

    const float* cb = c + b * 25;
    float fx = cb[16], sk = cb[17], cx = cb[18];
    float fy = cb[20], cy = cb[21];
    float ox = cb[3], oy = cb[7], oz = cb[11];

    // maxdist threshold (uniform, 16 broadcast loads)
    float m2 = 0.0f;
    #pragma unroll
    for (int i = 0; i < PREP_BLK; ++i) m2 = fmaxf(m2, gpart[b * PREP_BLK + i]);
    float thr = sqrtf(m2);

    // ---- ray setup: 4 rays per thread ----
    float px[RPT], py[RPT], pz[RPT], pn[RPT], dep[RPT], mxs[RPT];
    #pragma unroll
    for (int r = 0; r < RPT; ++r) {
        int m = tile * RAYS_PB + lane + 64 * r;
        int mm = min(m, M - 1);
        int i = mm / res, j = mm - i * res;
        float x = (j + 0.5f) / (float)res;
        float y = (i + 0.5f) / (float)res;
        float xl = (x - cx + cy * sk / fy - sk * y / fy) / fx;
        float yl = (y - cy) / fy;
        float wx = cb[0] * xl + cb[1] * yl + cb[2] + cb[3];
        float wy = cb[4] * xl + cb[5] * yl + cb[6] + cb[7];
        float wz = cb[8] * xl + cb[9] * yl + cb[10] + cb[11];
        float dx = wx - ox, dy = wy - oy, dz = wz - oz;
        float nrm = fmaxf(sqrtf(dx * dx + dy * dy + dz * dz), 1e-12f);
        dx /= nrm; dy /= nrm; dz /= nrm;
        float d = depth[(size_t)b * M + mm];
        dep[r] = d;
        px[r] = fmaf(d, dx, ox);
        py[r] = fmaf(d, dy, oy);
        pz[r] = fmaf(d, dz, oz);
        pn[r] = px[r] * px[r] + py[r] * py[r] + pz[r] * pz[r];
        mxs[r] = -3.4e38f;
    }

    // ---- scan this wave's point chunk: broadcast global loads ----
    {
        int cpw = (N + WAVES - 1) / WAVES;
        int s0 = min(w * cpw, N);
        int s1 = min(s0 + cpw, N);
        const float4* pq = pts4 + (size_t)b * N;
        #pragma unroll 4
        for (int k = s0; k < s1; ++k) {
            float4 q = pq[k];   // wave-uniform -> 1 L2 request, broadcast
            #pragma unroll
            for (int r = 0; r < RPT; ++r) {
                float s = fmaf(pz[r], q.z, q.w);
                s = fmaf(py[r], q.y, s);
                s = fmaf(px[r], q.x, s);
                mxs[r] = fmaxf(mxs[r], s);
            }
        }
    }

    // ---- cross-wave max combine ----
    #pragma unroll
    for (int r = 0; r < RPT; ++r) red[w][lane + 64 * r] = mxs[r];
    __syncthreads();

    float s = 0.f, cnt = 0.f;
    if (tid < RAYS_PB) {
        float mx = red[0][tid];
        #pragma unroll
        for (int ww = 1; ww < WAVES; ++ww) mx = fmaxf(mx, red[ww][tid]);
        // ray tid's pn/dep live in this thread's slot r == w (static select)
        float pnk = pn[0], dk = dep[0];
        #pragma unroll
        for (int r = 1; r < RPT; ++r) if (w == r) { pnk = pn[r]; dk = dep[r]; }
        int m = tile * RAYS_PB + tid;
        if (m < M) {
            float md = fmaxf(fmaf(-2.0f, mx, pnk), 0.0f);
            if (dk < thr) { s = md; cnt = 1.0f; }
        }
    }
    for (int off = 32; off; off >>= 1) {
        s += __shfl_down(s, off);
        cnt += __shfl_down(cnt, off);
    }
    if (tid < RAYS_PB && lane == 0) { bs[w] = s; bc[w] = cnt; }
    __syncthreads();
    if (tid == 0) {
        float S = 0.f, C = 0.f;
        #pragma unroll
        for (int ww = 0; ww < RPT; ++ww) { S += bs[ww]; C += bc[ww]; }
        partial[(size_t)b * gridDim.x + blockIdx.x] = make_float2(S, C);
    }
}

// ---------------------------------------------------------------------------
// Finalize: grid = B, one wave. nblk = 64 partials per batch.
// ---------------------------------------------------------------------------
__global__ __launch_bounds__(64) void finalize_kernel(
    const float2* __restrict__ partial, float* __restrict__ out, int nblk)
{
    int b = blockIdx.x;
    float S = 0.f, C = 0.f;
    for (int i = threadIdx.x; i < nblk; i += 64) {
        float2 p = partial[(size_t)b * nblk + i];
        S += p.x; C += p.y;
    }
    for (int off = 32; off; off >>= 1) {
        S += __shfl_down(S, off);
        C += __shfl_down(C, off);
    }
    if (threadIdx.x == 0) out[b] = S / fmaxf(C, 1.0f);
}

extern "C" void kernel_launch(void* const* d_in, const int* in_sizes, int n_in,
                              void* d_out, int out_size, void* d_ws, size_t ws_size,
                              hipStream_t stream) {
    const float* c     = (const float*)d_in[0];
    const float* depth = (const float*)d_in[1];
    const float* pc    = (const float*)d_in[2];

    int B = in_sizes[0] / 25;
    int M = in_sizes[1] / B;
    int N = in_sizes[2] / (3 * B);
    int res = 1;
    while (res * res < M) ++res;

    char* base = (char*)d_ws;
    float4* pts4 = (float4*)base;
    size_t o1 = (size_t)B * N * sizeof(float4);
    o1 = (o1 + 255) & ~(size_t)255;
    float* gpart = (float*)(base + o1);
    size_t o2 = o1 + (size_t)B * PREP_BLK * sizeof(float);
    o2 = (o2 + 255) & ~(size_t)255;
    float2* partial = (float2*)(base + o2);

    int ntiles = (M + RAYS_PB - 1) / RAYS_PB;

    prep_kernel<<<dim3(PREP_BLK, B), PREP_T, 0, stream>>>(c, pc, pts4, gpart, N);
    chamfer_main<<<dim3(ntiles, B), TPB, 0, stream>>>(c, depth, pts4, gpart,
                                                      partial, res, M, N);
    finalize_kernel<<<B, 64, 0, stream>>>(partial, (float*)d_out, ntiles);
}

// Round 5
// 33.371 us; speedup vs baseline: 1.0745x; 1.0745x over previous
//
#include <hip/hip_runtime.h>
#include <math.h>

#define TPB 512
#define WAVES 8
#define RAYS_PB 512      // rays per block (64 lanes * RPT)
#define RPT 8            // rays per thread
#define MAXK 1024        // points staged in LDS (16 KB as float4)
#define PREP_BLK 16      // prep blocks per batch
#define PREP_T 128

// ---------------------------------------------------------------------------
// Prep: pack points as (qx,qy,qz,-0.5|q|^2); per-block maxdist^2 partials.
// grid = (PREP_BLK, B), block = 128.
// ---------------------------------------------------------------------------
__global__ __launch_bounds__(PREP_T) void prep_kernel(
    const float* __restrict__ c, const float* __restrict__ pc,
    float4* __restrict__ pts4, float* __restrict__ gpart, int N)
{
    int b = blockIdx.y, blk = blockIdx.x;
    const float* cb = c + b * 25;
    float ox = cb[3], oy = cb[7], oz = cb[11];
    const float* p = pc + (size_t)b * N * 3;
    int per = (N + PREP_BLK - 1) / PREP_BLK;
    int n0 = blk * per;
    int n1 = min(n0 + per, N);
    float mx = 0.0f;
    for (int n = n0 + threadIdx.x; n < n1; n += PREP_T) {
        float qx = p[n * 3], qy = p[n * 3 + 1], qz = p[n * 3 + 2];
        float qn = qx * qx + qy * qy + qz * qz;
        pts4[(size_t)b * N + n] = make_float4(qx, qy, qz, -0.5f * qn);
        float dx = qx - ox, dy = qy - oy, dz = qz - oz;
        mx = fmaxf(mx, dx * dx + dy * dy + dz * dz);
    }
    for (int off = 32; off; off >>= 1) mx = fmaxf(mx, __shfl_down(mx, off));
    __shared__ float sm[PREP_T / 64];
    if ((threadIdx.x & 63) == 0) sm[threadIdx.x >> 6] = mx;
    __syncthreads();
    if (threadIdx.x == 0) {
        float m2 = sm[0];
        for (int i = 1; i < PREP_T / 64; ++i) m2 = fmaxf(m2, sm[i]);
        gpart[b * PREP_BLK + blk] = m2;
    }
}

// ---------------------------------------------------------------------------
// Main: grid = (ceil(M/512), 2, B), block = 512 (8 waves).
// Block (tile,h,b): 512 rays vs point-half h (K points). Half staged once in
// LDS as float4; wave w scans its K/8 sub-chunk for all 512 rays (8 rays per
// thread in registers, LDS broadcast ds_read_b128 amortized over 8 rays).
// Cross-wave max in LDS; writes per-ray half-max (+pn when h==0).
// Deterministic: unique slots, no atomics.
//   min_n d2 = pn - 2 * max_n (p.q - 0.5|q|^2),  q.w = -0.5|q|^2
// ---------------------------------------------------------------------------
__global__ __launch_bounds__(TPB) void chamfer_main(
    const float* __restrict__ c, const float* __restrict__ depth,
    const float4* __restrict__ pts4,
    float* __restrict__ partmax,   // [B*2][M]
    float* __restrict__ pnbuf,     // [B][M]
    int res, int M, int N, int K)
{
    __shared__ float4 spts[MAXK];             // 16 KB
    __shared__ float red[WAVES][RAYS_PB];     // 16 KB

    int tile = blockIdx.x, h = blockIdx.y, b = blockIdx.z;
    int tid = threadIdx.x, w = tid >> 6, lane = tid & 63;

    const float* cb = c + b * 25;
    float fx = cb[16], sk = cb[17], cx = cb[18];
    float fy = cb[20], cy = cb[21];
    float ox = cb[3], oy = cb[7], oz = cb[11];

    // ---- ray setup: 8 rays per thread ----
    float px[RPT], py[RPT], pz[RPT], pn[RPT], mxs[RPT];
    #pragma unroll
    for (int r = 0; r < RPT; ++r) {
        int m = tile * RAYS_PB + lane + 64 * r;
        int mm = min(m, M - 1);
        int i = mm / res, j = mm - i * res;
        float x = (j + 0.5f) / (float)res;
        float y = (i + 0.5f) / (float)res;
        float xl = (x - cx + cy * sk / fy - sk * y / fy) / fx;
        float yl = (y - cy) / fy;
        float wx = cb[0] * xl + cb[1] * yl + cb[2] + cb[3];
        float wy = cb[4] * xl + cb[5] * yl + cb[6] + cb[7];
        float wz = cb[8] * xl + cb[9] * yl + cb[10] + cb[11];
        float dx = wx - ox, dy = wy - oy, dz = wz - oz;
        float nrm = fmaxf(sqrtf(dx * dx + dy * dy + dz * dz), 1e-12f);
        dx /= nrm; dy /= nrm; dz /= nrm;
        float d = depth[(size_t)b * M + mm];
        px[r] = fmaf(d, dx, ox);
        py[r] = fmaf(d, dy, oy);
        pz[r] = fmaf(d, dz, oz);
        pn[r] = px[r] * px[r] + py[r] * py[r] + pz[r] * pz[r];
        mxs[r] = -3.4e38f;
    }

    // ---- this half's points, staged once in LDS ----
    int ks = h * K;
    int khalf = max(0, min(N - ks, K));        // <= MAXK for N <= 2*MAXK
    for (int c0 = 0; c0 < khalf; c0 += MAXK) {
        int kc = min(khalf - c0, MAXK);
        if (c0) __syncthreads();
        const float4* src = pts4 + (size_t)b * N + ks + c0;
        for (int k = tid; k < kc; k += TPB) spts[k] = src[k];
        __syncthreads();

        int cpw = (kc + WAVES - 1) / WAVES;
        int s0 = min(w * cpw, kc);
        int s1 = min(s0 + cpw, kc);
        #pragma unroll 4
        for (int k = s0; k < s1; ++k) {
            float4 q = spts[k];   // wave-uniform broadcast, conflict-free
            #pragma unroll
            for (int r = 0; r < RPT; ++r) {
                float s = fmaf(pz[r], q.z, q.w);
                s = fmaf(py[r], q.y, s);
                s = fmaf(px[r], q.x, s);
                mxs[r] = fmaxf(mxs[r], s);
            }
        }
    }

    // ---- cross-wave max combine; thread tid owns ray tid ----
    #pragma unroll
    for (int r = 0; r < RPT; ++r) red[w][lane + 64 * r] = mxs[r];
    __syncthreads();

    float mx = red[0][tid];
    #pragma unroll
    for (int ww = 1; ww < WAVES; ++ww) mx = fmaxf(mx, red[ww][tid]);
    // ray tid's pn lives in this thread's slot r == w (static select)
    float pnk = pn[0];
    #pragma unroll
    for (int r = 1; r < RPT; ++r) if (w == r) pnk = pn[r];
    int m = tile * RAYS_PB + tid;
    if (m < M) {
        partmax[((size_t)(b * 2 + h)) * M + m] = mx;
        if (h == 0) pnbuf[(size_t)b * M + m] = pnk;
    }
}

// ---------------------------------------------------------------------------
// Finalize: grid = B, block = 1024. Combine halves, masked mean.
// ---------------------------------------------------------------------------
__global__ __launch_bounds__(1024) void finalize_kernel(
    const float* __restrict__ partmax, const float* __restrict__ pnbuf,
    const float* __restrict__ gpart, const float* __restrict__ depth,
    float* __restrict__ out, int M)
{
    int b = blockIdx.x;
    float m2 = 0.0f;
    #pragma unroll
    for (int i = 0; i < PREP_BLK; ++i) m2 = fmaxf(m2, gpart[b * PREP_BLK + i]);
    float thr = sqrtf(m2);

    float s = 0.f, cnt = 0.f;
    for (int m = threadIdx.x; m < M; m += 1024) {
        float mx = fmaxf(partmax[(size_t)(2 * b) * M + m],
                         partmax[(size_t)(2 * b + 1) * M + m]);
        float md = fmaxf(fmaf(-2.0f, mx, pnbuf[(size_t)b * M + m]), 0.0f);
        if (depth[(size_t)b * M + m] < thr) { s += md; cnt += 1.0f; }
    }
    for (int off = 32; off; off >>= 1) {
        s += __shfl_down(s, off);
        cnt += __shfl_down(cnt, off);
    }
    __shared__ float ss[16], sc[16];
    int w = threadIdx.x >> 6;
    if ((threadIdx.x & 63) == 0) { ss[w] = s; sc[w] = cnt; }
    __syncthreads();
    if (threadIdx.x == 0) {
        float S = 0.f, C = 0.f;
        #pragma unroll
        for (int ww = 0; ww < 16; ++ww) { S += ss[ww]; C += sc[ww]; }
        out[b] = S / fmaxf(C, 1.0f);
    }
}

extern "C" void kernel_launch(void* const* d_in, const int* in_sizes, int n_in,
                              void* d_out, int out_size, void* d_ws, size_t ws_size,
                              hipStream_t stream) {
    const float* c     = (const float*)d_in[0];
    const float* depth = (const float*)d_in[1];
    const float* pc    = (const float*)d_in[2];

    int B = in_sizes[0] / 25;
    int M = in_sizes[1] / B;
    int N = in_sizes[2] / (3 * B);
    int res = 1;
    while (res * res < M) ++res;

    int K = (N + 1) / 2;   // points per half

    char* base = (char*)d_ws;
    float4* pts4 = (float4*)base;
    size_t o = (size_t)B * N * sizeof(float4);
    o = (o + 255) & ~(size_t)255;
    float* gpart = (float*)(base + o);
    o += (size_t)B * PREP_BLK * sizeof(float);
    o = (o + 255) & ~(size_t)255;
    float* partmax = (float*)(base + o);
    o += (size_t)B * 2 * M * sizeof(float);
    o = (o + 255) & ~(size_t)255;
    float* pnbuf = (float*)(base + o);

    int ntiles = (M + RAYS_PB - 1) / RAYS_PB;

    prep_kernel<<<dim3(PREP_BLK, B), PREP_T, 0, stream>>>(c, pc, pts4, gpart, N);
    chamfer_main<<<dim3(ntiles, 2, B), TPB, 0, stream>>>(c, depth, pts4,
                                                         partmax, pnbuf,
                                                         res, M, N, K);
    finalize_kernel<<<B, 1024, 0, stream>>>(partmax, pnbuf, gpart, depth,
                                            (float*)d_out, M);
}

// Round 6
// 21.824 us; speedup vs baseline: 1.6430x; 1.5291x over previous
//
#include <hip/hip_runtime.h>
#include <math.h>

#define TPB 512
#define WAVES 8
#define RAYS_PB 256      // rays per block
#define RPT 4            // rays per thread (RAYS_PB / 64)
#define MAXPTS 2048      // points staged in LDS per chunk (32 KB as float4)

// ---------------------------------------------------------------------------
// Fused main: grid = (ceil(M/256), B), block = 512 (8 waves).
// Each block: 256 rays vs ALL N points.
//  - stages pc directly into LDS as (qx,qy,qz,-0.5|q|^2)  (no prep kernel)
//  - computes the COMPLETE maxdist locally (it sees all N points)
//  - wave w scans its N/8 point chunk for all 256 rays (4 rays/thread in
//    registers; each LDS broadcast ds_read_b128 amortized over 4 rays)
//  - cross-wave max combine in LDS, masked sum -> ONE float2 per block.
// Fully deterministic: fixed-order in-block reductions, no atomics.
//   min_n d2 = pn - 2 * max_n (p.q - 0.5|q|^2),  q.w = -0.5|q|^2
// ---------------------------------------------------------------------------
__global__ __launch_bounds__(TPB) void chamfer_main(
    const float* __restrict__ c, const float* __restrict__ depth,
    const float* __restrict__ pc, float2* __restrict__ partial,
    int res, int M, int N)
{
    __shared__ float4 spts[MAXPTS];           // 32 KB
    __shared__ float red[WAVES][RAYS_PB];     // 8 KB
    __shared__ float smax[WAVES];
    __shared__ float bs[RPT], bc[RPT];

    int tile = blockIdx.x, b = blockIdx.y;
    int tid = threadIdx.x, w = tid >> 6, lane = tid & 63;

    const float* cb = c + b * 25;
    float fx = cb[16], sk = cb[17], cx = cb[18];
    float fy = cb[20], cy = cb[21];
    float ox = cb[3], oy = cb[7], oz = cb[11];

    // ---- ray setup: 4 rays per thread (overlaps staging-load latency) ----
    float px[RPT], py[RPT], pz[RPT], pn[RPT], dep[RPT], mxs[RPT];
    #pragma unroll
    for (int r = 0; r < RPT; ++r) {
        int m = tile * RAYS_PB + lane + 64 * r;
        int mm = min(m, M - 1);
        int i = mm / res, j = mm - i * res;
        float x = (j + 0.5f) / (float)res;
        float y = (i + 0.5f) / (float)res;
        float xl = (x - cx + cy * sk / fy - sk * y / fy) / fx;
        float yl = (y - cy) / fy;
        float wx = cb[0] * xl + cb[1] * yl + cb[2] + cb[3];
        float wy = cb[4] * xl + cb[5] * yl + cb[6] + cb[7];
        float wz = cb[8] * xl + cb[9] * yl + cb[10] + cb[11];
        float dx = wx - ox, dy = wy - oy, dz = wz - oz;
        float nrm = fmaxf(sqrtf(dx * dx + dy * dy + dz * dz), 1e-12f);
        dx /= nrm; dy /= nrm; dz /= nrm;
        float d = depth[(size_t)b * M + mm];
        dep[r] = d;
        px[r] = fmaf(d, dx, ox);
        py[r] = fmaf(d, dy, oy);
        pz[r] = fmaf(d, dz, oz);
        pn[r] = px[r] * px[r] + py[r] * py[r] + pz[r] * pz[r];
        mxs[r] = -3.4e38f;
    }

    // ---- stage + scan all N points (chunked; N<=MAXPTS -> single pass) ----
    float mdl = 0.0f;   // squared distances >= 0
    for (int n0 = 0; n0 < N; n0 += MAXPTS) {
        int kc = min(N - n0, MAXPTS);
        if (n0) __syncthreads();   // previous chunk's reads complete
        const float* src = pc + ((size_t)b * N + n0) * 3;
        for (int p = tid; p < kc; p += TPB) {
            float qx = src[3 * p], qy = src[3 * p + 1], qz = src[3 * p + 2];
            float qn = qx * qx + qy * qy + qz * qz;
            spts[p] = make_float4(qx, qy, qz, -0.5f * qn);
            float dx = qx - ox, dy = qy - oy, dz = qz - oz;
            mdl = fmaxf(mdl, dx * dx + dy * dy + dz * dz);
        }
        __syncthreads();

        int cpw = (kc + WAVES - 1) / WAVES;
        int s0 = min(w * cpw, kc);
        int s1 = min(s0 + cpw, kc);
        #pragma unroll 8
        for (int k = s0; k < s1; ++k) {
            float4 q = spts[k];   // wave-uniform broadcast, conflict-free
            #pragma unroll
            for (int r = 0; r < RPT; ++r) {
                float s = fmaf(pz[r], q.z, q.w);
                s = fmaf(py[r], q.y, s);
                s = fmaf(px[r], q.x, s);
                mxs[r] = fmaxf(mxs[r], s);
            }
        }
    }

    // ---- per-wave maxdist partial + per-ray max handoff ----
    for (int off = 32; off; off >>= 1) mdl = fmaxf(mdl, __shfl_down(mdl, off));
    if (lane == 0) smax[w] = mdl;
    #pragma unroll
    for (int r = 0; r < RPT; ++r) red[w][lane + 64 * r] = mxs[r];
    __syncthreads();

    // ---- combine: thread tid (<256) owns ray tid ----
    float s = 0.f, cnt = 0.f;
    if (tid < RAYS_PB) {
        float m2 = smax[0];
        #pragma unroll
        for (int ww = 1; ww < WAVES; ++ww) m2 = fmaxf(m2, smax[ww]);
        float thr = sqrtf(m2);

        float mx = red[0][tid];
        #pragma unroll
        for (int ww = 1; ww < WAVES; ++ww) mx = fmaxf(mx, red[ww][tid]);
        // ray tid's pn/dep live in this thread's slot r == w (static select)
        float pnk = pn[0], dk = dep[0];
        #pragma unroll
        for (int r = 1; r < RPT; ++r) if (w == r) { pnk = pn[r]; dk = dep[r]; }
        int m = tile * RAYS_PB + tid;
        if (m < M) {
            float md = fmaxf(fmaf(-2.0f, mx, pnk), 0.0f);
            if (dk < thr) { s = md; cnt = 1.0f; }
        }
    }
    for (int off = 32; off; off >>= 1) {
        s += __shfl_down(s, off);
        cnt += __shfl_down(cnt, off);
    }
    if (tid < RAYS_PB && lane == 0) { bs[w] = s; bc[w] = cnt; }
    __syncthreads();
    if (tid == 0) {
        float S = 0.f, C = 0.f;
        #pragma unroll
        for (int ww = 0; ww < RPT; ++ww) { S += bs[ww]; C += bc[ww]; }
        partial[(size_t)b * gridDim.x + blockIdx.x] = make_float2(S, C);
    }
}

// ---------------------------------------------------------------------------
// Finalize: ONE block; wave w reduces batch w's ntiles partials.
// ---------------------------------------------------------------------------
__global__ __launch_bounds__(1024) void finalize_kernel(
    const float2* __restrict__ partial, float* __restrict__ out,
    int ntiles, int B)
{
    int w = threadIdx.x >> 6, lane = threadIdx.x & 63;
    if (w >= B) return;
    float S = 0.f, C = 0.f;
    for (int i = lane; i < ntiles; i += 64) {
        float2 p = partial[(size_t)w * ntiles + i];
        S += p.x; C += p.y;
    }
    for (int off = 32; off; off >>= 1) {
        S += __shfl_down(S, off);
        C += __shfl_down(C, off);
    }
    if (lane == 0) out[w] = S / fmaxf(C, 1.0f);
}

extern "C" void kernel_launch(void* const* d_in, const int* in_sizes, int n_in,
                              void* d_out, int out_size, void* d_ws, size_t ws_size,
                              hipStream_t stream) {
    const float* c     = (const float*)d_in[0];
    const float* depth = (const float*)d_in[1];
    const float* pc    = (const float*)d_in[2];

    int B = in_sizes[0] / 25;
    int M = in_sizes[1] / B;
    int N = in_sizes[2] / (3 * B);
    int res = 1;
    while (res * res < M) ++res;

    float2* partial = (float2*)d_ws;

    int ntiles = (M + RAYS_PB - 1) / RAYS_PB;

    chamfer_main<<<dim3(ntiles, B), TPB, 0, stream>>>(c, depth, pc, partial,
                                                      res, M, N);
    finalize_kernel<<<1, B * 64, 0, stream>>>(partial, (float*)d_out,
                                              ntiles, B);
}